// Round 22
// baseline (237.670 us; speedup 1.0000x reference)
//
#include <hip/hip_runtime.h>

#define NNODES 40960
#define NEDGES 81920
#define NG     1024
#define NCOMBO 512

// ---- inline-asm W-load pipeline (dwordx4): 4 loads per batch ----
// Offsets are literal; batch covers 4 consecutive k at byte offs {A0..A3}.
#define ISSUE4(V, p, A0, A1, A2, A3) asm volatile( \
  "global_load_dwordx4 %0, %4, off offset:" #A0 "\n\t" \
  "global_load_dwordx4 %1, %4, off offset:" #A1 "\n\t" \
  "global_load_dwordx4 %2, %4, off offset:" #A2 "\n\t" \
  "global_load_dwordx4 %3, %4, off offset:" #A3 "\n\t" \
  : "=v"(V[0]), "=v"(V[1]), "=v"(V[2]), "=v"(V[3]) : "v"(p))

// counted wait WITHOUT tied operands (r21: scalar-component ties forced
// pre-wait v_mov copies of in-flight load dests -> race). Rule-18 fix:
// sched_barrier(0) right after the waitcnt pins all dependent FMAs below it.
#define WAIT4(N) do { \
    asm volatile("s_waitcnt vmcnt(" #N ")" ::: "memory"); \
    __builtin_amdgcn_sched_barrier(0); \
  } while (0)

// ---------- fused node encoder: x[n,:], then out_init[n,:] = bias + x@root ---
__global__ __launch_bounds__(256) void k_node(
    const int* __restrict__ nf, const float* __restrict__ emb,
    const float* __restrict__ root, const float* __restrict__ bias,
    float* __restrict__ x, float* __restrict__ out) {
    __shared__ float sx[4][64];
    const int t = threadIdx.x;
    const int ln = t >> 6;                 // local node 0..3
    const int d  = t & 63;
    const int n  = blockIdx.x * 4 + ln;
    const int* nfr = nf + n * 9;
    float acc = 0.f;
#pragma unroll
    for (int c = 0; c < 9; ++c) {
        int idx = nfr[c];
        acc += emb[((c << 7) + idx) * 64 + d];
    }
    x[n * 64 + d] = acc;
    sx[ln][d] = acc;
    __syncthreads();
    if (d < 32) {
        float o = bias[d];
#pragma unroll
        for (int k = 0; k < 64; ++k) o += sx[ln][k] * root[k * 32 + d];
        out[n * 32 + d] = o;
    }
}

// ---------- h1[c,:] = relu(etab[c] @ gW1), etab computed in-LDS ----------
__global__ __launch_bounds__(256) void k_h1(
    const float* __restrict__ bemb, const float* __restrict__ gW1,
    float* __restrict__ h1) {
    __shared__ float se[16];
    const int b = blockIdx.x, t = threadIdx.x;
    const int c = b >> 2;
    const int n = ((b & 3) << 8) + t;
    if (t < 16) {
        int f0 = c >> 6, f1 = (c >> 3) & 7, f2 = c & 7;
        se[t] = bemb[f0 * 16 + t] + bemb[(8 + f1) * 16 + t] +
                bemb[(16 + f2) * 16 + t];
    }
    __syncthreads();
    float acc = 0.f;
#pragma unroll
    for (int k = 0; k < 16; ++k) acc += se[k] * gW1[k * 1024 + n];
    h1[c * 1024 + n] = fmaxf(acc, 0.f);
}

// ---------- tiled GEMM, 64x64 block tile, 4x4 micro tile, split-K over z ------
template <int BM, int BN, int BK, int TM, int TN>
__global__ __launch_bounds__(256)
void k_gemm_tiled(const float* __restrict__ A, const float* __restrict__ B,
                  const float* __restrict__ bias, float* __restrict__ C,
                  float* __restrict__ Cp, int M, int N, int K, int KS, int relu) {
    constexpr int TX = BN / TN;                 // 16
    constexpr int TY = BM / TM;                 // 16
    static_assert(TX * TY == 256, "block must be 256 threads");
    __shared__ float As[BK][BM + 4];            // transposed A tile
    __shared__ float Bs[BK][BN + 4];
    const int tx = threadIdx.x % TX, ty = threadIdx.x / TX;
    const int row0 = blockIdx.y * BM, col0 = blockIdx.x * BN;
    const int z = blockIdx.z;
    const int k_begin = z * KS, k_end = k_begin + KS;

    const int am = threadIdx.x >> 2;            // 0..63
    const int ak = (threadIdx.x & 3) << 2;      // 0,4,8,12
    const int bk = threadIdx.x >> 4;            // 0..15
    const int bn = (threadIdx.x & 15) << 2;     // 0..60

    float acc[TM][TN] = {};
    for (int k0 = k_begin; k0 < k_end; k0 += BK) {
        float4 av = *reinterpret_cast<const float4*>(&A[(row0 + am) * K + k0 + ak]);
        float4 bv = *reinterpret_cast<const float4*>(&B[(k0 + bk) * N + col0 + bn]);
        As[ak + 0][am] = av.x;
        As[ak + 1][am] = av.y;
        As[ak + 2][am] = av.z;
        As[ak + 3][am] = av.w;
        *reinterpret_cast<float4*>(&Bs[bk][bn]) = bv;
        __syncthreads();
#pragma unroll
        for (int k = 0; k < BK; ++k) {
            float a[TM], b[TN];
            *reinterpret_cast<float4*>(a) =
                *reinterpret_cast<const float4*>(&As[k][ty * TM]);
            *reinterpret_cast<float4*>(b) =
                *reinterpret_cast<const float4*>(&Bs[k][tx * TN]);
#pragma unroll
            for (int i = 0; i < TM; ++i)
#pragma unroll
                for (int j = 0; j < TN; ++j) acc[i][j] += a[i] * b[j];
        }
        __syncthreads();
    }

    const int MN = M * N;
    if (gridDim.z == 1) {
#pragma unroll
        for (int i = 0; i < TM; ++i) {
            int r = row0 + ty * TM + i;
            float4 v;
            v.x = acc[i][0]; v.y = acc[i][1]; v.z = acc[i][2]; v.w = acc[i][3];
            int c = col0 + tx * TN;
            if (bias) { v.x += bias[c]; v.y += bias[c+1]; v.z += bias[c+2]; v.w += bias[c+3]; }
            if (relu) { v.x = fmaxf(v.x,0.f); v.y = fmaxf(v.y,0.f);
                        v.z = fmaxf(v.z,0.f); v.w = fmaxf(v.w,0.f); }
            *reinterpret_cast<float4*>(&C[r * N + c]) = v;
        }
    } else {
        float* dstp = Cp + z * MN;
#pragma unroll
        for (int i = 0; i < TM; ++i) {
            int r = row0 + ty * TM + i;
            float4 v;
            v.x = acc[i][0]; v.y = acc[i][1]; v.z = acc[i][2]; v.w = acc[i][3];
            *reinterpret_cast<float4*>(&dstp[r * N + col0 + tx * TN]) = v;
        }
    }
}

// ---------- split-K reduce: C = relu?(sum_z Cp[z] + bias) ----------
__global__ void k_reduceK(const float* __restrict__ Cp, const float* __restrict__ bias,
                          float* __restrict__ C, int MN, int N, int nz, int relu) {
    int i4 = (blockIdx.x * 256 + threadIdx.x) * 4;
    if (i4 >= MN) return;
    float4 acc = *reinterpret_cast<const float4*>(&Cp[i4]);
    for (int z = 1; z < nz; ++z) {
        float4 t = *reinterpret_cast<const float4*>(&Cp[z * MN + i4]);
        acc.x += t.x; acc.y += t.y; acc.z += t.z; acc.w += t.w;
    }
    if (bias) {
        int c = i4 % N;
        acc.x += bias[c]; acc.y += bias[c + 1]; acc.z += bias[c + 2]; acc.w += bias[c + 3];
    }
    if (relu) {
        acc.x = fmaxf(acc.x, 0.f); acc.y = fmaxf(acc.y, 0.f);
        acc.z = fmaxf(acc.z, 0.f); acc.w = fmaxf(acc.w, 0.f);
    }
    *reinterpret_cast<float4*>(&C[i4]) = acc;
}

// ---------- NNConv message + scatter: wide-load (dwordx4) asm pipeline ------
// Block = 32 edges x 8 threads; thread owns cols 4o..4o+3 of one edge.
// Per k, an edge's 8 lanes fetch one contiguous 128B region -> same line
// count as round-16, but 4x fewer load INSTRUCTIONS and 4x fewer waves.
// 16 batches of 4 dwordx4; 3 batches (12 loads) in flight; counted vmcnt(8).
// Waits use sched_barrier(0) fencing (no tied copies -> no pre-wait reads).
// FMA order k-ascending per column. Atomic scatter unchanged.
__global__ __launch_bounds__(256) void k_msg4a(
    const float* __restrict__ x, const float* __restrict__ wtab,
    const int* __restrict__ ef, const int* __restrict__ src,
    const int* __restrict__ dst, float* __restrict__ out) {
    __shared__ float sx[32][64];
    const int t = threadIdx.x;
    const int e_base = blockIdx.x * 32;
#pragma unroll
    for (int i = 0; i < 8; ++i) {          // stage 32 x rows cooperatively
        int idx = t + i * 256;
        int r = idx >> 6, cl = idx & 63;
        sx[r][cl] = x[src[e_base + r] * 64 + cl];
    }
    const int slot = t >> 3;               // edge 0..31
    const int o4   = (t & 7) << 2;         // col group 0,4,...,28
    const int e = e_base + slot;
    const int d = dst[e];
    const int c = (ef[e * 3] << 6) | (ef[e * 3 + 1] << 3) | ef[e * 3 + 2];
    const float* wl = wtab + c * 2048 + o4;   // k=0..31: byte offs k*128
    const float* wh = wl + 1024;              // k=32..63
    __syncthreads();                          // drains all prior vmcnt/lgkmcnt

    float4 W0[4], W1[4], W2[4], W3[4];
    float4 acc = make_float4(0.f, 0.f, 0.f, 0.f);
    const float* sxe = sx[slot];

#define FMA4(W, KB) \
    { _Pragma("unroll") for (int i = 0; i < 4; ++i) { \
        float q = sxe[(KB) + i]; \
        acc.x += q * W[i].x; acc.y += q * W[i].y; \
        acc.z += q * W[i].z; acc.w += q * W[i].w; } }

    ISSUE4(W0, wl, 0, 128, 256, 384);          // b0  (4 out)
    ISSUE4(W1, wl, 512, 640, 768, 896);        // b1  (8)
    ISSUE4(W2, wl, 1024, 1152, 1280, 1408);    // b2  (12)
    WAIT4(8); ISSUE4(W3, wl, 1536, 1664, 1792, 1920); FMA4(W0, 0);
    WAIT4(8); ISSUE4(W0, wl, 2048, 2176, 2304, 2432); FMA4(W1, 4);
    WAIT4(8); ISSUE4(W1, wl, 2560, 2688, 2816, 2944); FMA4(W2, 8);
    WAIT4(8); ISSUE4(W2, wl, 3072, 3200, 3328, 3456); FMA4(W3, 12);
    WAIT4(8); ISSUE4(W3, wl, 3584, 3712, 3840, 3968); FMA4(W0, 16);
    WAIT4(8); ISSUE4(W0, wh, 0, 128, 256, 384);       FMA4(W1, 20);
    WAIT4(8); ISSUE4(W1, wh, 512, 640, 768, 896);     FMA4(W2, 24);
    WAIT4(8); ISSUE4(W2, wh, 1024, 1152, 1280, 1408); FMA4(W3, 28);
    WAIT4(8); ISSUE4(W3, wh, 1536, 1664, 1792, 1920); FMA4(W0, 32);
    WAIT4(8); ISSUE4(W0, wh, 2048, 2176, 2304, 2432); FMA4(W1, 36);
    WAIT4(8); ISSUE4(W1, wh, 2560, 2688, 2816, 2944); FMA4(W2, 40);
    WAIT4(8); ISSUE4(W2, wh, 3072, 3200, 3328, 3456); FMA4(W3, 44);
    WAIT4(8); ISSUE4(W3, wh, 3584, 3712, 3840, 3968); FMA4(W0, 48);
    WAIT4(8); FMA4(W1, 52);
    WAIT4(4); FMA4(W2, 56);
    WAIT4(0); FMA4(W3, 60);
#undef FMA4

    float* op = out + d * 32 + o4;
    atomicAdd(op + 0, acc.x);
    atomicAdd(op + 1, acc.y);
    atomicAdd(op + 2, acc.z);
    atomicAdd(op + 3, acc.w);
}

// ---------- fused readout tail: f1 -> f2 -> f3 -> f4 -> out, 4 graphs/block --
__global__ __launch_bounds__(256) void k_tail2(
    const float* __restrict__ f1,
    const float* __restrict__ mW2, const float* __restrict__ mb2,
    const float* __restrict__ mW3, const float* __restrict__ mb3,
    const float* __restrict__ mW4, const float* __restrict__ mb4,
    const float* __restrict__ mW5, const float* __restrict__ mb5,
    float* __restrict__ outv) {
    __shared__ float s1[4][256];
    __shared__ float s2[4][128];
    __shared__ float s3[4][32];
    __shared__ float s4[4][8];
    const int t  = threadIdx.x;
    const int g0 = blockIdx.x * 4;
#pragma unroll
    for (int i = 0; i < 4; ++i) {
        int idx = t + i * 256;
        s1[idx >> 8][idx & 255] = f1[g0 * 256 + idx];
    }
    __syncthreads();
#pragma unroll
    for (int i = 0; i < 2; ++i) {
        int idx = t + i * 256;
        int g = idx >> 7, cc = idx & 127;
        float acc = mb2[cc];
#pragma unroll 8
        for (int k = 0; k < 256; ++k) acc += s1[g][k] * mW2[k * 128 + cc];
        s2[g][cc] = fmaxf(acc, 0.f);
    }
    __syncthreads();
    const int w = t >> 6, lane = t & 63;
    if (lane < 32) {
        float acc = mb3[lane];
#pragma unroll 8
        for (int k = 0; k < 128; ++k) acc += s2[w][k] * mW3[k * 32 + lane];
        s3[w][lane] = fmaxf(acc, 0.f);
    }
    __syncthreads();
    if (lane < 8) {
        float acc = mb4[lane];
#pragma unroll
        for (int k = 0; k < 32; ++k) acc += s3[w][k] * mW4[k * 8 + lane];
        s4[w][lane] = fmaxf(acc, 0.f);
    }
    __syncthreads();
    if (lane == 0) {
        float acc = mb5[0];
#pragma unroll
        for (int k = 0; k < 8; ++k) acc += s4[w][k] * mW5[k];
        outv[g0 + w] = acc;
    }
}

extern "C" void kernel_launch(void* const* d_in, const int* in_sizes, int n_in,
                              void* d_out, int out_size, void* d_ws, size_t ws_size,
                              hipStream_t stream) {
    const int*   nf      = (const int*)d_in[0];
    const int*   ef      = (const int*)d_in[1];
    const int*   eidx    = (const int*)d_in[2];
    const float* atom_emb= (const float*)d_in[4];
    const float* bond_emb= (const float*)d_in[5];
    const float* gW1     = (const float*)d_in[6];
    const float* gW2     = (const float*)d_in[7];
    const float* gW3     = (const float*)d_in[8];
    const float* root    = (const float*)d_in[9];
    const float* cbias   = (const float*)d_in[10];
    const float* mW1     = (const float*)d_in[11];
    const float* mb1     = (const float*)d_in[12];
    const float* mW2     = (const float*)d_in[13];
    const float* mb2     = (const float*)d_in[14];
    const float* mW3     = (const float*)d_in[15];
    const float* mb3     = (const float*)d_in[16];
    const float* mW4     = (const float*)d_in[17];
    const float* mb4     = (const float*)d_in[18];
    const float* mW5     = (const float*)d_in[19];
    const float* mb5     = (const float*)d_in[20];

    const int* src = eidx;
    const int* dst = eidx + NEDGES;

    float* ws = (float*)d_ws;
    float* x    = ws;                        // 40960*64   = 2621440
    float* out  = x + 2621440;               // 40960*32   = 1310720
    float* h1   = out + 1310720;             // 512*1024   = 524288
    float* h2   = h1 + 524288;               // 512*256    = 131072
    float* wtab = h2 + 131072;               // 512*2048   = 1048576
    float* f1   = wtab + 1048576;            // 1024*256   = 262144
    float* part = f1 + 262144;               // 2097152 (8 MB split-K partials)

    // 1. fused atom encoder + root transform
    k_node<<<NNODES / 4, 256, 0, stream>>>(nf, atom_emb, root, cbias, x, out);
    // 2. h1 = relu(etab @ gW1), etab computed in-LDS per block
    k_h1<<<NCOMBO * 4, 256, 0, stream>>>(bond_emb, gW1, h1);
    // 3. h2 = relu(h1 @ gW2): 512x256, K=1024, split 16x64
    k_gemm_tiled<64, 64, 16, 4, 4><<<dim3(4, 8, 16), 256, 0, stream>>>(
        h1, gW2, nullptr, nullptr, part, NCOMBO, 256, 1024, 64, 0);
    k_reduceK<<<131072 / 1024, 256, 0, stream>>>(part, nullptr, h2, 131072, 256, 16, 1);
    // 4. wtab = h2 @ gW3: 512x2048, K=256, split 2x128
    k_gemm_tiled<64, 64, 16, 4, 4><<<dim3(32, 8, 2), 256, 0, stream>>>(
        h2, gW3, nullptr, nullptr, part, NCOMBO, 2048, 256, 128, 0);
    k_reduceK<<<1048576 / 1024, 256, 0, stream>>>(part, nullptr, wtab, 1048576, 2048, 2, 0);
    // 5. per-edge message + scatter: dwordx4 asm pipeline (counted vmcnt)
    k_msg4a<<<NEDGES / 32, 256, 0, stream>>>(x, wtab, ef, src, dst, out);
    // 6. f1 = relu(dense @ mW1 + mb1): 1024x256, K=1280, split 8x160
    k_gemm_tiled<64, 64, 16, 4, 4><<<dim3(4, 16, 8), 256, 0, stream>>>(
        out, mW1, nullptr, nullptr, part, NG, 256, 1280, 160, 0);
    k_reduceK<<<262144 / 1024, 256, 0, stream>>>(part, mb1, f1, 262144, 256, 8, 1);
    // 7. fused tail: f2, f3, f4, final
    k_tail2<<<NG / 4, 256, 0, stream>>>(f1, mW2, mb2, mW3, mb3, mW4, mb4,
                                        mW5, mb5, (float*)d_out);
}

// Round 23
// 225.611 us; speedup vs baseline: 1.0535x; 1.0535x over previous
//
#include <hip/hip_runtime.h>

#define NNODES 40960
#define NEDGES 81920
#define NG     1024
#define NCOMBO 512

// ---- inline-asm W-load pipeline helpers (compiler cannot re-serialize) ----
#define ISSUE_LO(w, p) asm volatile( \
  "global_load_dword %0, %16, off\n\t" \
  "global_load_dword %1, %16, off offset:128\n\t" \
  "global_load_dword %2, %16, off offset:256\n\t" \
  "global_load_dword %3, %16, off offset:384\n\t" \
  "global_load_dword %4, %16, off offset:512\n\t" \
  "global_load_dword %5, %16, off offset:640\n\t" \
  "global_load_dword %6, %16, off offset:768\n\t" \
  "global_load_dword %7, %16, off offset:896\n\t" \
  "global_load_dword %8, %16, off offset:1024\n\t" \
  "global_load_dword %9, %16, off offset:1152\n\t" \
  "global_load_dword %10, %16, off offset:1280\n\t" \
  "global_load_dword %11, %16, off offset:1408\n\t" \
  "global_load_dword %12, %16, off offset:1536\n\t" \
  "global_load_dword %13, %16, off offset:1664\n\t" \
  "global_load_dword %14, %16, off offset:1792\n\t" \
  "global_load_dword %15, %16, off offset:1920\n\t" \
  : "=v"(w[0]),"=v"(w[1]),"=v"(w[2]),"=v"(w[3]),"=v"(w[4]),"=v"(w[5]), \
    "=v"(w[6]),"=v"(w[7]),"=v"(w[8]),"=v"(w[9]),"=v"(w[10]),"=v"(w[11]), \
    "=v"(w[12]),"=v"(w[13]),"=v"(w[14]),"=v"(w[15]) \
  : "v"(p))

#define ISSUE_HI(w, p) asm volatile( \
  "global_load_dword %0, %16, off offset:2048\n\t" \
  "global_load_dword %1, %16, off offset:2176\n\t" \
  "global_load_dword %2, %16, off offset:2304\n\t" \
  "global_load_dword %3, %16, off offset:2432\n\t" \
  "global_load_dword %4, %16, off offset:2560\n\t" \
  "global_load_dword %5, %16, off offset:2688\n\t" \
  "global_load_dword %6, %16, off offset:2816\n\t" \
  "global_load_dword %7, %16, off offset:2944\n\t" \
  "global_load_dword %8, %16, off offset:3072\n\t" \
  "global_load_dword %9, %16, off offset:3200\n\t" \
  "global_load_dword %10, %16, off offset:3328\n\t" \
  "global_load_dword %11, %16, off offset:3456\n\t" \
  "global_load_dword %12, %16, off offset:3584\n\t" \
  "global_load_dword %13, %16, off offset:3712\n\t" \
  "global_load_dword %14, %16, off offset:3840\n\t" \
  "global_load_dword %15, %16, off offset:3968\n\t" \
  : "=v"(w[0]),"=v"(w[1]),"=v"(w[2]),"=v"(w[3]),"=v"(w[4]),"=v"(w[5]), \
    "=v"(w[6]),"=v"(w[7]),"=v"(w[8]),"=v"(w[9]),"=v"(w[10]),"=v"(w[11]), \
    "=v"(w[12]),"=v"(w[13]),"=v"(w[14]),"=v"(w[15]) \
  : "v"(p))

// counted wait; batch values threaded through as "+v" so consuming FMAs
// carry a data dependency on this block (cannot be hoisted above it).
#define WAIT16(N, w) asm volatile("s_waitcnt vmcnt(" #N ")" \
  : "+v"(w[0]),"+v"(w[1]),"+v"(w[2]),"+v"(w[3]),"+v"(w[4]),"+v"(w[5]), \
    "+v"(w[6]),"+v"(w[7]),"+v"(w[8]),"+v"(w[9]),"+v"(w[10]),"+v"(w[11]), \
    "+v"(w[12]),"+v"(w[13]),"+v"(w[14]),"+v"(w[15]))

// ---------- fused node encoder: x[n,:], then out_init[n,:] = bias + x@root ---
__global__ __launch_bounds__(256) void k_node(
    const int* __restrict__ nf, const float* __restrict__ emb,
    const float* __restrict__ root, const float* __restrict__ bias,
    float* __restrict__ x, float* __restrict__ out) {
    __shared__ float sx[4][64];
    const int t = threadIdx.x;
    const int ln = t >> 6;                 // local node 0..3
    const int d  = t & 63;
    const int n  = blockIdx.x * 4 + ln;
    const int* nfr = nf + n * 9;
    float acc = 0.f;
#pragma unroll
    for (int c = 0; c < 9; ++c) {
        int idx = nfr[c];
        acc += emb[((c << 7) + idx) * 64 + d];
    }
    x[n * 64 + d] = acc;
    sx[ln][d] = acc;
    __syncthreads();
    if (d < 32) {
        float o = bias[d];
#pragma unroll
        for (int k = 0; k < 64; ++k) o += sx[ln][k] * root[k * 32 + d];
        out[n * 32 + d] = o;
    }
}

// ---------- h1[c,:] = relu(etab[c] @ gW1), etab computed in-LDS ----------
__global__ __launch_bounds__(256) void k_h1(
    const float* __restrict__ bemb, const float* __restrict__ gW1,
    float* __restrict__ h1) {
    __shared__ float se[16];
    const int b = blockIdx.x, t = threadIdx.x;
    const int c = b >> 2;
    const int n = ((b & 3) << 8) + t;
    if (t < 16) {
        int f0 = c >> 6, f1 = (c >> 3) & 7, f2 = c & 7;
        se[t] = bemb[f0 * 16 + t] + bemb[(8 + f1) * 16 + t] +
                bemb[(16 + f2) * 16 + t];
    }
    __syncthreads();
    float acc = 0.f;
#pragma unroll
    for (int k = 0; k < 16; ++k) acc += se[k] * gW1[k * 1024 + n];
    h1[c * 1024 + n] = fmaxf(acc, 0.f);
}

// ---------- tiled GEMM, 64x64 block tile, 4x4 micro tile, split-K over z ------
template <int BM, int BN, int BK, int TM, int TN>
__global__ __launch_bounds__(256)
void k_gemm_tiled(const float* __restrict__ A, const float* __restrict__ B,
                  const float* __restrict__ bias, float* __restrict__ C,
                  float* __restrict__ Cp, int M, int N, int K, int KS, int relu) {
    constexpr int TX = BN / TN;                 // 16
    constexpr int TY = BM / TM;                 // 16
    static_assert(TX * TY == 256, "block must be 256 threads");
    __shared__ float As[BK][BM + 4];            // transposed A tile
    __shared__ float Bs[BK][BN + 4];
    const int tx = threadIdx.x % TX, ty = threadIdx.x / TX;
    const int row0 = blockIdx.y * BM, col0 = blockIdx.x * BN;
    const int z = blockIdx.z;
    const int k_begin = z * KS, k_end = k_begin + KS;

    const int am = threadIdx.x >> 2;            // 0..63
    const int ak = (threadIdx.x & 3) << 2;      // 0,4,8,12
    const int bk = threadIdx.x >> 4;            // 0..15
    const int bn = (threadIdx.x & 15) << 2;     // 0..60

    float acc[TM][TN] = {};
    for (int k0 = k_begin; k0 < k_end; k0 += BK) {
        float4 av = *reinterpret_cast<const float4*>(&A[(row0 + am) * K + k0 + ak]);
        float4 bv = *reinterpret_cast<const float4*>(&B[(k0 + bk) * N + col0 + bn]);
        As[ak + 0][am] = av.x;
        As[ak + 1][am] = av.y;
        As[ak + 2][am] = av.z;
        As[ak + 3][am] = av.w;
        *reinterpret_cast<float4*>(&Bs[bk][bn]) = bv;
        __syncthreads();
#pragma unroll
        for (int k = 0; k < BK; ++k) {
            float a[TM], b[TN];
            *reinterpret_cast<float4*>(a) =
                *reinterpret_cast<const float4*>(&As[k][ty * TM]);
            *reinterpret_cast<float4*>(b) =
                *reinterpret_cast<const float4*>(&Bs[k][tx * TN]);
#pragma unroll
            for (int i = 0; i < TM; ++i)
#pragma unroll
                for (int j = 0; j < TN; ++j) acc[i][j] += a[i] * b[j];
        }
        __syncthreads();
    }

    const int MN = M * N;
    if (gridDim.z == 1) {
#pragma unroll
        for (int i = 0; i < TM; ++i) {
            int r = row0 + ty * TM + i;
            float4 v;
            v.x = acc[i][0]; v.y = acc[i][1]; v.z = acc[i][2]; v.w = acc[i][3];
            int c = col0 + tx * TN;
            if (bias) { v.x += bias[c]; v.y += bias[c+1]; v.z += bias[c+2]; v.w += bias[c+3]; }
            if (relu) { v.x = fmaxf(v.x,0.f); v.y = fmaxf(v.y,0.f);
                        v.z = fmaxf(v.z,0.f); v.w = fmaxf(v.w,0.f); }
            *reinterpret_cast<float4*>(&C[r * N + c]) = v;
        }
    } else {
        float* dstp = Cp + z * MN;
#pragma unroll
        for (int i = 0; i < TM; ++i) {
            int r = row0 + ty * TM + i;
            float4 v;
            v.x = acc[i][0]; v.y = acc[i][1]; v.z = acc[i][2]; v.w = acc[i][3];
            *reinterpret_cast<float4*>(&dstp[r * N + col0 + tx * TN]) = v;
        }
    }
}

// ---------- split-K reduce: C = relu?(sum_z Cp[z] + bias) ----------
__global__ void k_reduceK(const float* __restrict__ Cp, const float* __restrict__ bias,
                          float* __restrict__ C, int MN, int N, int nz, int relu) {
    int i4 = (blockIdx.x * 256 + threadIdx.x) * 4;
    if (i4 >= MN) return;
    float4 acc = *reinterpret_cast<const float4*>(&Cp[i4]);
    for (int z = 1; z < nz; ++z) {
        float4 t = *reinterpret_cast<const float4*>(&Cp[z * MN + i4]);
        acc.x += t.x; acc.y += t.y; acc.z += t.z; acc.w += t.w;
    }
    if (bias) {
        int c = i4 % N;
        acc.x += bias[c]; acc.y += bias[c + 1]; acc.z += bias[c + 2]; acc.w += bias[c + 3];
    }
    if (relu) {
        acc.x = fmaxf(acc.x, 0.f); acc.y = fmaxf(acc.y, 0.f);
        acc.z = fmaxf(acc.z, 0.f); acc.w = fmaxf(acc.w, 0.f);
    }
    *reinterpret_cast<float4*>(&C[i4]) = acc;
}

// ---------- NNConv message + scatter: asm-pipelined W loads ----------
// Block = 8 edges x 32 cols. x rows staged in LDS. 64 W loads issued as
// 4 x 16-load asm batches with counted vmcnt waits (48 in flight peak).
// FMA order = k ascending, bit-identical to round-9 k_msg. This is the
// measured-best message kernel (~39.5 us, r16/r18). Verified envelope:
// r17 (2-edge deepening) crashed; r22 (dwordx4 wide) was slower (49 us,
// LDS bank conflicts + occupancy loss). Do not extend.
__global__ __launch_bounds__(256) void k_msga(
    const float* __restrict__ x, const float* __restrict__ wtab,
    const int* __restrict__ ef, const int* __restrict__ src,
    const int* __restrict__ dst, float* __restrict__ out) {
    __shared__ float sx[8][64];
    const int t = threadIdx.x;
    const int e_base = blockIdx.x * 8;
    {   // cooperative x staging: 8 rows x 64 floats, 2 per thread
        int idx = t;
        int r = idx >> 6, cl = idx & 63;
        sx[r][cl] = x[src[e_base + r] * 64 + cl];
        idx = t + 256;
        r = idx >> 6; cl = idx & 63;
        sx[r][cl] = x[src[e_base + r] * 64 + cl];
    }
    const int slot = t >> 5, o = t & 31;
    const int e = e_base + slot;
    const int d = dst[e];
    const int c = (ef[e * 3] << 6) | (ef[e * 3 + 1] << 3) | ef[e * 3 + 2];
    const float* wl = wtab + c * 2048 + o;     // k=0..31 at byte offsets k*128
    const float* wh = wl + 1024;               // k=32..63
    __syncthreads();                           // drains all prior vmcnt/lgkmcnt

    float wA[16], wB[16], wC[16], wD[16];
    ISSUE_LO(wA, wl);                          // b0: k 0..15   (16 in flight)
    ISSUE_HI(wB, wl);                          // b1: k 16..31  (32)
    ISSUE_LO(wC, wh);                          // b2: k 32..47  (48)
    float acc = 0.f;
    WAIT16(32, wA);                            // b0 complete
    ISSUE_HI(wD, wh);                          // b3: k 48..63  (<=48)
#pragma unroll
    for (int i = 0; i < 16; ++i) acc += sx[slot][i] * wA[i];
    WAIT16(32, wB);                            // b1 complete
#pragma unroll
    for (int i = 0; i < 16; ++i) acc += sx[slot][16 + i] * wB[i];
    WAIT16(16, wC);                            // b2 complete
#pragma unroll
    for (int i = 0; i < 16; ++i) acc += sx[slot][32 + i] * wC[i];
    WAIT16(0, wD);                             // b3 complete
#pragma unroll
    for (int i = 0; i < 16; ++i) acc += sx[slot][48 + i] * wD[i];
    atomicAdd(&out[d * 32 + o], acc);
}

// ---------- fused readout tail: f1 -> f2 -> f3 -> f4 -> out, 4 graphs/block --
__global__ __launch_bounds__(256) void k_tail2(
    const float* __restrict__ f1,
    const float* __restrict__ mW2, const float* __restrict__ mb2,
    const float* __restrict__ mW3, const float* __restrict__ mb3,
    const float* __restrict__ mW4, const float* __restrict__ mb4,
    const float* __restrict__ mW5, const float* __restrict__ mb5,
    float* __restrict__ outv) {
    __shared__ float s1[4][256];
    __shared__ float s2[4][128];
    __shared__ float s3[4][32];
    __shared__ float s4[4][8];
    const int t  = threadIdx.x;
    const int g0 = blockIdx.x * 4;
#pragma unroll
    for (int i = 0; i < 4; ++i) {
        int idx = t + i * 256;
        s1[idx >> 8][idx & 255] = f1[g0 * 256 + idx];
    }
    __syncthreads();
#pragma unroll
    for (int i = 0; i < 2; ++i) {
        int idx = t + i * 256;
        int g = idx >> 7, cc = idx & 127;
        float acc = mb2[cc];
#pragma unroll 8
        for (int k = 0; k < 256; ++k) acc += s1[g][k] * mW2[k * 128 + cc];
        s2[g][cc] = fmaxf(acc, 0.f);
    }
    __syncthreads();
    const int w = t >> 6, lane = t & 63;
    if (lane < 32) {
        float acc = mb3[lane];
#pragma unroll 8
        for (int k = 0; k < 128; ++k) acc += s2[w][k] * mW3[k * 32 + lane];
        s3[w][lane] = fmaxf(acc, 0.f);
    }
    __syncthreads();
    if (lane < 8) {
        float acc = mb4[lane];
#pragma unroll
        for (int k = 0; k < 32; ++k) acc += s3[w][k] * mW4[k * 8 + lane];
        s4[w][lane] = fmaxf(acc, 0.f);
    }
    __syncthreads();
    if (lane == 0) {
        float acc = mb5[0];
#pragma unroll
        for (int k = 0; k < 8; ++k) acc += s4[w][k] * mW5[k];
        outv[g0 + w] = acc;
    }
}

extern "C" void kernel_launch(void* const* d_in, const int* in_sizes, int n_in,
                              void* d_out, int out_size, void* d_ws, size_t ws_size,
                              hipStream_t stream) {
    const int*   nf      = (const int*)d_in[0];
    const int*   ef      = (const int*)d_in[1];
    const int*   eidx    = (const int*)d_in[2];
    const float* atom_emb= (const float*)d_in[4];
    const float* bond_emb= (const float*)d_in[5];
    const float* gW1     = (const float*)d_in[6];
    const float* gW2     = (const float*)d_in[7];
    const float* gW3     = (const float*)d_in[8];
    const float* root    = (const float*)d_in[9];
    const float* cbias   = (const float*)d_in[10];
    const float* mW1     = (const float*)d_in[11];
    const float* mb1     = (const float*)d_in[12];
    const float* mW2     = (const float*)d_in[13];
    const float* mb2     = (const float*)d_in[14];
    const float* mW3     = (const float*)d_in[15];
    const float* mb3     = (const float*)d_in[16];
    const float* mW4     = (const float*)d_in[17];
    const float* mb4     = (const float*)d_in[18];
    const float* mW5     = (const float*)d_in[19];
    const float* mb5     = (const float*)d_in[20];

    const int* src = eidx;
    const int* dst = eidx + NEDGES;

    float* ws = (float*)d_ws;
    float* x    = ws;                        // 40960*64   = 2621440
    float* out  = x + 2621440;               // 40960*32   = 1310720
    float* h1   = out + 1310720;             // 512*1024   = 524288
    float* h2   = h1 + 524288;               // 512*256    = 131072
    float* wtab = h2 + 131072;               // 512*2048   = 1048576
    float* f1   = wtab + 1048576;            // 1024*256   = 262144
    float* part = f1 + 262144;               // 2097152 (8 MB split-K partials)

    // 1. fused atom encoder + root transform
    k_node<<<NNODES / 4, 256, 0, stream>>>(nf, atom_emb, root, cbias, x, out);
    // 2. h1 = relu(etab @ gW1), etab computed in-LDS per block
    k_h1<<<NCOMBO * 4, 256, 0, stream>>>(bond_emb, gW1, h1);
    // 3. h2 = relu(h1 @ gW2): 512x256, K=1024, split 16x64
    k_gemm_tiled<64, 64, 16, 4, 4><<<dim3(4, 8, 16), 256, 0, stream>>>(
        h1, gW2, nullptr, nullptr, part, NCOMBO, 256, 1024, 64, 0);
    k_reduceK<<<131072 / 1024, 256, 0, stream>>>(part, nullptr, h2, 131072, 256, 16, 1);
    // 4. wtab = h2 @ gW3: 512x2048, K=256, split 2x128
    k_gemm_tiled<64, 64, 16, 4, 4><<<dim3(32, 8, 2), 256, 0, stream>>>(
        h2, gW3, nullptr, nullptr, part, NCOMBO, 2048, 256, 128, 0);
    k_reduceK<<<1048576 / 1024, 256, 0, stream>>>(part, nullptr, wtab, 1048576, 2048, 2, 0);
    // 5. per-edge message + scatter: asm-pipelined W loads (counted vmcnt)
    k_msga<<<NEDGES / 8, 256, 0, stream>>>(x, wtab, ef, src, dst, out);
    // 6. f1 = relu(dense @ mW1 + mb1): 1024x256, K=1280, split 8x160
    k_gemm_tiled<64, 64, 16, 4, 4><<<dim3(4, 16, 8), 256, 0, stream>>>(
        out, mW1, nullptr, nullptr, part, NG, 256, 1280, 160, 0);
    k_reduceK<<<262144 / 1024, 256, 0, stream>>>(part, mb1, f1, 262144, 256, 8, 1);
    // 7. fused tail: f2, f3, f4, final
    k_tail2<<<NG / 4, 256, 0, stream>>>(f1, mW2, mb2, mW3, mb3, mW4, mb4,
                                        mW5, mb5, (float*)d_out);
}